// Round 4
// baseline (544.586 us; speedup 1.0000x reference)
//
#include <hip/hip_runtime.h>
#include <hip/hip_bf16.h>

typedef float f32x4 __attribute__((ext_vector_type(4)));
typedef short s16x8 __attribute__((ext_vector_type(8)));
typedef unsigned short u16;
typedef unsigned short u16x4 __attribute__((ext_vector_type(4)));

#define N_TOK 4096
#define DIM 1024
#define HID 4096
#define NE 8
#define MAXMB 72

__device__ __forceinline__ u16 f2bf(float f) {
  unsigned u = __float_as_uint(f);
  u += 0x7fffu + ((u >> 16) & 1u);   // round-to-nearest-even
  return (u16)(u >> 16);
}

__device__ __forceinline__ void gload16(const u16* g, u16* l) {
  __builtin_amdgcn_global_load_lds(
      (const __attribute__((address_space(1))) unsigned int*)g,
      (__attribute__((address_space(3))) unsigned int*)l, 16, 0, 0);
}

__global__ void init_kernel(int* counts) {
  if (threadIdx.x < NE) counts[threadIdx.x] = 0;
}

__global__ __launch_bounds__(256) void gate_kernel(
    const float* __restrict__ x, const float* __restrict__ gw,
    const float* __restrict__ gb, int* __restrict__ counts,
    int* __restrict__ tlist, int* __restrict__ eid, int* __restrict__ pos,
    float* __restrict__ wgt) {
  int t = blockIdx.x * 4 + (threadIdx.x >> 6);
  int lane = threadIdx.x & 63;
  float acc[NE];
  #pragma unroll
  for (int e = 0; e < NE; ++e) acc[e] = 0.f;
  const float* xr = x + (size_t)t * DIM;
  for (int d = lane; d < DIM; d += 64) {
    float xv = xr[d];
    const float* g = gw + d * NE;
    #pragma unroll
    for (int e = 0; e < NE; ++e) acc[e] += xv * g[e];
  }
  #pragma unroll
  for (int off = 32; off > 0; off >>= 1) {
    #pragma unroll
    for (int e = 0; e < NE; ++e) acc[e] += __shfl_down(acc[e], off);
  }
  if (lane == 0) {
    #pragma unroll
    for (int e = 0; e < NE; ++e) acc[e] += gb[e];
    int i0 = 0; float v0 = acc[0];
    #pragma unroll
    for (int e = 1; e < NE; ++e) if (acc[e] > v0) { v0 = acc[e]; i0 = e; }
    int i1 = -1; float v1 = -1e30f;
    #pragma unroll
    for (int e = 0; e < NE; ++e) if (e != i0 && acc[e] > v1) { v1 = acc[e]; i1 = e; }
    float z = expf(v1 - v0);            // v0 >= v1
    float s0 = 1.f / (1.f + z);
    float s1 = z / (1.f + z);
    int p0 = atomicAdd(&counts[i0], 1);
    tlist[i0 * N_TOK + p0] = t * 2 + 0;
    eid[2 * t] = i0; pos[2 * t] = p0; wgt[2 * t] = s0;
    int p1 = atomicAdd(&counts[i1], 1);
    tlist[i1 * N_TOK + p1] = t * 2 + 1;
    eid[2 * t + 1] = i1; pos[2 * t + 1] = p1; wgt[2 * t + 1] = s1;
  }
}

// Builds dense m-block schedule: experts padded to 128-row slot regions.
__global__ void scan_kernel(const int* __restrict__ counts, int* __restrict__ offs,
                            int* __restrict__ poffs, int* __restrict__ nmb,
                            int* __restrict__ mb2e, int* __restrict__ mb2m0) {
  if (threadIdx.x == 0) {
    int s = 0, p = 0, mb = 0;
    for (int e = 0; e < NE; ++e) {
      offs[e] = s; poffs[e] = p;
      int nb = (counts[e] + 127) >> 7;
      for (int i = 0; i < nb; ++i) { mb2e[mb] = e; mb2m0[mb] = i * 128; ++mb; }
      s += counts[e]; p += nb * 128;
    }
    offs[NE] = s; poffs[NE] = p;
    nmb[0] = mb;
    for (int i = mb; i < MAXMB; ++i) { mb2e[i] = 0; mb2m0[i] = 0; }
  }
}

// x (fp32) -> xb (bf16), elementwise
__global__ __launch_bounds__(256) void x2bf_kernel(const float* __restrict__ x,
                                                   u16* __restrict__ xb) {
  int i = (blockIdx.x * 256 + threadIdx.x) * 4;
  float4 v = *(const float4*)&x[i];
  u16x4 o = {f2bf(v.x), f2bf(v.y), f2bf(v.z), f2bf(v.w)};
  *(u16x4*)&xb[i] = o;
}

// in[e][R][C] fp32 -> out[e][C][R] bf16 (64x64 LDS tile transpose)
__global__ __launch_bounds__(256) void transpose_bf16_kernel(
    const float* __restrict__ in, u16* __restrict__ out, int R, int C) {
  __shared__ u16 tile[64][65];
  int e = blockIdx.z;
  int c0 = blockIdx.x * 64, r0 = blockIdx.y * 64;
  int tid = threadIdx.x;
  int rr = tid >> 4;          // 0..15
  int cc = (tid & 15) * 4;    // 0..60
  const float* src = in + (size_t)e * R * C + (size_t)r0 * C + c0;
  #pragma unroll
  for (int rd = 0; rd < 4; ++rd) {
    int r = rd * 16 + rr;
    float4 v = *(const float4*)&src[(size_t)r * C + cc];
    tile[r][cc + 0] = f2bf(v.x);
    tile[r][cc + 1] = f2bf(v.y);
    tile[r][cc + 2] = f2bf(v.z);
    tile[r][cc + 3] = f2bf(v.w);
  }
  __syncthreads();
  u16* dst = out + (size_t)e * R * C + (size_t)c0 * R + r0;
  #pragma unroll
  for (int rd = 0; rd < 4; ++rd) {
    int oc = rd * 16 + rr;    // output row (= input col)
    u16x4 o;
    o[0] = tile[cc + 0][oc];
    o[1] = tile[cc + 1][oc];
    o[2] = tile[cc + 2][oc];
    o[3] = tile[cc + 3][oc];
    *(u16x4*)&dst[(size_t)oc * R + cc] = o;
  }
}

// GEMM1: h[pslot, H] = relu(x[token, D] * w1t[e]^T + b1[e]) -> bf16
// 128x128x32, double-buffered 2-phase prefetch
__global__ __launch_bounds__(256) void gemm1_kernel(
    const u16* __restrict__ xb, const u16* __restrict__ w1t,
    const float* __restrict__ b1, const int* __restrict__ counts,
    const int* __restrict__ poffs, const int* __restrict__ nmb,
    const int* __restrict__ mb2e, const int* __restrict__ mb2m0,
    const int* __restrict__ tlist, u16* __restrict__ hbuf) {
  int mb = blockIdx.x;
  if (mb >= nmb[0]) return;
  int e = mb2e[mb];
  int m0 = mb2m0[mb];
  int ne = counts[e];
  int n0 = blockIdx.y * 128;
  int tid = threadIdx.x;

  __shared__ u16 Als[2][128 * 32];
  __shared__ u16 Bls[2][128 * 32];

  int sr = tid >> 2;          // 0..63 : row within 64-row half
  int sc = (tid & 3) * 8;     // k element offset for 16B chunk
  const u16* aAdr0; const u16* aAdr1;
  const u16* bAdr0; const u16* bAdr1;
  {
    int tr = m0 + sr;
    int idx = tr < ne ? tr : ne - 1;
    aAdr0 = xb + (size_t)(tlist[e * N_TOK + idx] >> 1) * DIM + sc;
    tr = m0 + 64 + sr;
    idx = tr < ne ? tr : ne - 1;
    aAdr1 = xb + (size_t)(tlist[e * N_TOK + idx] >> 1) * DIM + sc;
    bAdr0 = w1t + ((size_t)e * HID + n0 + sr) * DIM + sc;
    bAdr1 = w1t + ((size_t)e * HID + n0 + 64 + sr) * DIM + sc;
  }
  u16* aLb = &Als[0][tid * 8];   // + cur*4096 + half*2048
  u16* bLb = &Bls[0][tid * 8];

  int lane = tid & 63;
  int wv = tid >> 6;
  int wr = (wv >> 1) * 64, wc = (wv & 1) * 64;
  int fr = lane & 15, fq = lane >> 4;

  f32x4 acc[4][4];
  #pragma unroll
  for (int m = 0; m < 4; ++m)
    #pragma unroll
    for (int n = 0; n < 4; ++n) { f32x4 z = {0.f, 0.f, 0.f, 0.f}; acc[m][n] = z; }

  // prologue: stage tile 0 into buffer 0
  gload16(aAdr0, aLb);
  gload16(aAdr1, aLb + 2048);
  gload16(bAdr0, bLb);
  gload16(bAdr1, bLb + 2048);

  int cur = 0;
  for (int k0 = 0; k0 < DIM; k0 += 32) {
    __syncthreads();                       // drains vmcnt: buf[cur] ready
    int kn = k0 + 32;
    if (kn < DIM) {                        // prefetch next tile into buf[cur^1]
      int nb = (cur ^ 1) * 4096;
      gload16(aAdr0 + kn, aLb + nb);
      gload16(aAdr1 + kn, aLb + nb + 2048);
      gload16(bAdr0 + kn, bLb + nb);
      gload16(bAdr1 + kn, bLb + nb + 2048);
    }
    const u16* Ac = &Als[cur][0];
    const u16* Bc = &Bls[cur][0];
    s16x8 af[4], bfr[4];
    #pragma unroll
    for (int m = 0; m < 4; ++m)
      af[m] = *(const s16x8*)&Ac[(wr + m * 16 + fr) * 32 + fq * 8];
    #pragma unroll
    for (int n = 0; n < 4; ++n)
      bfr[n] = *(const s16x8*)&Bc[(wc + n * 16 + fr) * 32 + fq * 8];
    #pragma unroll
    for (int m = 0; m < 4; ++m)
      #pragma unroll
      for (int n = 0; n < 4; ++n)
        acc[m][n] = __builtin_amdgcn_mfma_f32_16x16x32_bf16(af[m], bfr[n], acc[m][n], 0, 0, 0);
    cur ^= 1;
  }

  int pbase = poffs[e] + m0;
  float bias[4];
  #pragma unroll
  for (int n = 0; n < 4; ++n) bias[n] = b1[e * HID + n0 + wc + n * 16 + fr];
  #pragma unroll
  for (int m = 0; m < 4; ++m) {
    #pragma unroll
    for (int j = 0; j < 4; ++j) {
      int row = wr + m * 16 + fq * 4 + j;
      if (m0 + row < ne) {
        u16* hr = hbuf + (size_t)(pbase + row) * HID + n0;
        #pragma unroll
        for (int n = 0; n < 4; ++n) {
          int col = wc + n * 16 + fr;
          float v = acc[m][n][j] + bias[n];
          hr[col] = f2bf(fmaxf(v, 0.f));
        }
      }
    }
  }
}

// GEMM2: y[pslot, D] = h[pslot, H] * w2t[e]^T + b2[e] -> fp32
// 128x64x32, double-buffered 2-phase prefetch
__global__ __launch_bounds__(256) void gemm2_kernel(
    const u16* __restrict__ hbuf, const u16* __restrict__ w2t,
    const float* __restrict__ b2, const int* __restrict__ counts,
    const int* __restrict__ poffs, const int* __restrict__ nmb,
    const int* __restrict__ mb2e, const int* __restrict__ mb2m0,
    float* __restrict__ ybuf) {
  int mb = blockIdx.x;
  if (mb >= nmb[0]) return;
  int e = mb2e[mb];
  int m0 = mb2m0[mb];
  int ne = counts[e];
  int n0 = blockIdx.y * 64;
  int tid = threadIdx.x;
  int pbase = poffs[e] + m0;

  __shared__ u16 Als[2][128 * 32];
  __shared__ u16 Bls[2][64 * 32];

  int sr = tid >> 2;          // 0..63
  int sc = (tid & 3) * 8;
  const u16* aAdr0; const u16* aAdr1; const u16* bAdr0;
  {
    int ar = m0 + sr;
    int idx = ar < ne ? ar : ne - 1;
    aAdr0 = hbuf + (size_t)(poffs[e] + idx) * HID + sc;
    ar = m0 + 64 + sr;
    idx = ar < ne ? ar : ne - 1;
    aAdr1 = hbuf + (size_t)(poffs[e] + idx) * HID + sc;
    bAdr0 = w2t + ((size_t)e * DIM + n0 + sr) * HID + sc;
  }
  u16* aLb = &Als[0][tid * 8];   // + cur*4096 + half*2048
  u16* bLb = &Bls[0][tid * 8];   // + cur*2048

  int lane = tid & 63;
  int wv = tid >> 6;
  int wr = (wv >> 1) * 64, wc = (wv & 1) * 32;
  int fr = lane & 15, fq = lane >> 4;

  f32x4 acc[4][2];
  #pragma unroll
  for (int m = 0; m < 4; ++m)
    #pragma unroll
    for (int n = 0; n < 2; ++n) { f32x4 z = {0.f, 0.f, 0.f, 0.f}; acc[m][n] = z; }

  gload16(aAdr0, aLb);
  gload16(aAdr1, aLb + 2048);
  gload16(bAdr0, bLb);

  int cur = 0;
  for (int k0 = 0; k0 < HID; k0 += 32) {
    __syncthreads();
    int kn = k0 + 32;
    if (kn < HID) {
      gload16(aAdr0 + kn, aLb + (cur ^ 1) * 4096);
      gload16(aAdr1 + kn, aLb + (cur ^ 1) * 4096 + 2048);
      gload16(bAdr0 + kn, bLb + (cur ^ 1) * 2048);
    }
    const u16* Ac = &Als[cur][0];
    const u16* Bc = &Bls[cur][0];
    s16x8 af[4], bfr[2];
    #pragma unroll
    for (int m = 0; m < 4; ++m)
      af[m] = *(const s16x8*)&Ac[(wr + m * 16 + fr) * 32 + fq * 8];
    #pragma unroll
    for (int n = 0; n < 2; ++n)
      bfr[n] = *(const s16x8*)&Bc[(wc + n * 16 + fr) * 32 + fq * 8];
    #pragma unroll
    for (int m = 0; m < 4; ++m)
      #pragma unroll
      for (int n = 0; n < 2; ++n)
        acc[m][n] = __builtin_amdgcn_mfma_f32_16x16x32_bf16(af[m], bfr[n], acc[m][n], 0, 0, 0);
    cur ^= 1;
  }

  float bias[2];
  #pragma unroll
  for (int n = 0; n < 2; ++n) bias[n] = b2[e * DIM + n0 + wc + n * 16 + fr];
  #pragma unroll
  for (int m = 0; m < 4; ++m) {
    #pragma unroll
    for (int j = 0; j < 4; ++j) {
      int row = wr + m * 16 + fq * 4 + j;
      if (m0 + row < ne) {
        float* yr = ybuf + (size_t)(pbase + row) * DIM + n0;
        #pragma unroll
        for (int n = 0; n < 2; ++n) {
          int col = wc + n * 16 + fr;
          yr[col] = acc[m][n][j] + bias[n];
        }
      }
    }
  }
}

__global__ __launch_bounds__(256) void combine_kernel(
    const int* __restrict__ eid, const int* __restrict__ pos,
    const float* __restrict__ wgt, const int* __restrict__ poffs,
    const float* __restrict__ ybuf, float* __restrict__ out) {
  int t = blockIdx.x;
  int e0 = eid[2 * t], e1 = eid[2 * t + 1];
  float w0 = wgt[2 * t], w1v = wgt[2 * t + 1];
  size_t g0 = (size_t)(poffs[e0] + pos[2 * t]) * DIM;
  size_t g1 = (size_t)(poffs[e1] + pos[2 * t + 1]) * DIM;
  int d = threadIdx.x * 4;
  float4 y0 = *(const float4*)&ybuf[g0 + d];
  float4 y1 = *(const float4*)&ybuf[g1 + d];
  float4 o;
  o.x = w0 * y0.x + w1v * y1.x;
  o.y = w0 * y0.y + w1v * y1.y;
  o.z = w0 * y0.z + w1v * y1.z;
  o.w = w0 * y0.w + w1v * y1.w;
  *(float4*)&out[(size_t)t * DIM + d] = o;
}

extern "C" void kernel_launch(void* const* d_in, const int* in_sizes, int n_in,
                              void* d_out, int out_size, void* d_ws, size_t ws_size,
                              hipStream_t stream) {
  const float* x  = (const float*)d_in[0];
  const float* gw = (const float*)d_in[1];
  const float* gb = (const float*)d_in[2];
  const float* w1 = (const float*)d_in[3];
  const float* b1 = (const float*)d_in[4];
  const float* w2 = (const float*)d_in[5];
  const float* b2 = (const float*)d_in[6];
  float* out = (float*)d_out;

  char* ws = (char*)d_ws;
  const size_t MB = 1ull << 20;
  // layout: w1t 64MB (ybuf aliases here after gemm1) | w2t 64MB | xb 8MB | hbuf 72MB | meta
  u16*   w1t    = (u16*)(ws);
  float* ybuf   = (float*)(ws);              // alias: w1t dead before gemm2 writes ybuf
  u16*   w2t    = (u16*)(ws + 64 * MB);
  u16*   xb     = (u16*)(ws + 128 * MB);
  u16*   hbuf   = (u16*)(ws + 136 * MB);
  char*  meta   = ws + 208 * MB;
  int*   eid    = (int*)(meta);
  int*   pos    = (int*)(meta + 32 * 1024);
  float* wgt    = (float*)(meta + 64 * 1024);
  int*   counts = (int*)(meta + 96 * 1024);
  int*   offs   = (int*)(meta + 96 * 1024 + 256);
  int*   poffs  = (int*)(meta + 96 * 1024 + 512);
  int*   nmb    = (int*)(meta + 96 * 1024 + 768);
  int*   mb2e   = (int*)(meta + 96 * 1024 + 1024);
  int*   mb2m0  = (int*)(meta + 96 * 1024 + 2048);
  int*   tlist  = (int*)(meta + 128 * 1024);

  init_kernel<<<1, 64, 0, stream>>>(counts);
  gate_kernel<<<N_TOK / 4, 256, 0, stream>>>(x, gw, gb, counts, tlist, eid, pos, wgt);
  scan_kernel<<<1, 64, 0, stream>>>(counts, offs, poffs, nmb, mb2e, mb2m0);
  x2bf_kernel<<<N_TOK * DIM / 1024, 256, 0, stream>>>(x, xb);
  // w1[e][D][H] -> w1t[e][H][D]
  transpose_bf16_kernel<<<dim3(HID / 64, DIM / 64, NE), 256, 0, stream>>>(w1, w1t, DIM, HID);
  // w2[e][H][D] -> w2t[e][D][H]
  transpose_bf16_kernel<<<dim3(DIM / 64, HID / 64, NE), 256, 0, stream>>>(w2, w2t, HID, DIM);
  gemm1_kernel<<<dim3(MAXMB, 32), 256, 0, stream>>>(xb, w1t, b1, counts, poffs, nmb, mb2e, mb2m0, tlist, hbuf);
  gemm2_kernel<<<dim3(MAXMB, 16), 256, 0, stream>>>(hbuf, w2t, b2, counts, poffs, nmb, mb2e, mb2m0, ybuf);
  combine_kernel<<<N_TOK, 256, 0, stream>>>(eid, pos, wgt, poffs, ybuf, out);
}

// Round 6
// 459.384 us; speedup vs baseline: 1.1855x; 1.1855x over previous
//
#include <hip/hip_runtime.h>
#include <hip/hip_bf16.h>

typedef float f32x4 __attribute__((ext_vector_type(4)));
typedef short s16x8 __attribute__((ext_vector_type(8)));
typedef unsigned short u16;
typedef unsigned short u16x4 __attribute__((ext_vector_type(4)));

#define N_TOK 4096
#define DIM 1024
#define HID 4096
#define NE 8
#define MAXMB 72

__device__ __forceinline__ u16 f2bf(float f) {
  unsigned u = __float_as_uint(f);
  u += 0x7fffu + ((u >> 16) & 1u);   // round-to-nearest-even
  return (u16)(u >> 16);
}

__device__ __forceinline__ void gload16(const u16* g, u16* l) {
  __builtin_amdgcn_global_load_lds(
      (const __attribute__((address_space(1))) unsigned int*)g,
      (__attribute__((address_space(3))) unsigned int*)l, 16, 0, 0);
}

__global__ void init_kernel(int* counts) {
  if (threadIdx.x < NE) counts[threadIdx.x] = 0;
}

__global__ __launch_bounds__(256) void gate_kernel(
    const float* __restrict__ x, const float* __restrict__ gw,
    const float* __restrict__ gb, int* __restrict__ counts,
    int* __restrict__ tlist, int* __restrict__ eid, int* __restrict__ pos,
    float* __restrict__ wgt) {
  int t = blockIdx.x * 4 + (threadIdx.x >> 6);
  int lane = threadIdx.x & 63;
  float acc[NE];
  #pragma unroll
  for (int e = 0; e < NE; ++e) acc[e] = 0.f;
  const float* xr = x + (size_t)t * DIM;
  for (int d = lane; d < DIM; d += 64) {
    float xv = xr[d];
    const float* g = gw + d * NE;
    #pragma unroll
    for (int e = 0; e < NE; ++e) acc[e] += xv * g[e];
  }
  #pragma unroll
  for (int off = 32; off > 0; off >>= 1) {
    #pragma unroll
    for (int e = 0; e < NE; ++e) acc[e] += __shfl_down(acc[e], off);
  }
  if (lane == 0) {
    #pragma unroll
    for (int e = 0; e < NE; ++e) acc[e] += gb[e];
    int i0 = 0; float v0 = acc[0];
    #pragma unroll
    for (int e = 1; e < NE; ++e) if (acc[e] > v0) { v0 = acc[e]; i0 = e; }
    int i1 = -1; float v1 = -1e30f;
    #pragma unroll
    for (int e = 0; e < NE; ++e) if (e != i0 && acc[e] > v1) { v1 = acc[e]; i1 = e; }
    float z = expf(v1 - v0);            // v0 >= v1
    float s0 = 1.f / (1.f + z);
    float s1 = z / (1.f + z);
    int p0 = atomicAdd(&counts[i0], 1);
    tlist[i0 * N_TOK + p0] = t * 2 + 0;
    eid[2 * t] = i0; pos[2 * t] = p0; wgt[2 * t] = s0;
    int p1 = atomicAdd(&counts[i1], 1);
    tlist[i1 * N_TOK + p1] = t * 2 + 1;
    eid[2 * t + 1] = i1; pos[2 * t + 1] = p1; wgt[2 * t + 1] = s1;
  }
}

// Builds dense m-block schedule: experts padded to 128-row slot regions.
__global__ void scan_kernel(const int* __restrict__ counts, int* __restrict__ offs,
                            int* __restrict__ poffs, int* __restrict__ nmb,
                            int* __restrict__ mb2e, int* __restrict__ mb2m0) {
  if (threadIdx.x == 0) {
    int s = 0, p = 0, mb = 0;
    for (int e = 0; e < NE; ++e) {
      offs[e] = s; poffs[e] = p;
      int nb = (counts[e] + 127) >> 7;
      for (int i = 0; i < nb; ++i) { mb2e[mb] = e; mb2m0[mb] = i * 128; ++mb; }
      s += counts[e]; p += nb * 128;
    }
    offs[NE] = s; poffs[NE] = p;
    nmb[0] = mb;
    for (int i = mb; i < MAXMB; ++i) { mb2e[i] = 0; mb2m0[i] = 0; }
  }
}

// x (fp32) -> xb (bf16), elementwise
__global__ __launch_bounds__(256) void x2bf_kernel(const float* __restrict__ x,
                                                   u16* __restrict__ xb) {
  int i = (blockIdx.x * 256 + threadIdx.x) * 4;
  float4 v = *(const float4*)&x[i];
  u16x4 o = {f2bf(v.x), f2bf(v.y), f2bf(v.z), f2bf(v.w)};
  *(u16x4*)&xb[i] = o;
}

// in[e][R][C] fp32 -> out[e][C][R] bf16 (64x64 LDS tile transpose)
__global__ __launch_bounds__(256) void transpose_bf16_kernel(
    const float* __restrict__ in, u16* __restrict__ out, int R, int C) {
  __shared__ u16 tile[64][65];
  int e = blockIdx.z;
  int c0 = blockIdx.x * 64, r0 = blockIdx.y * 64;
  int tid = threadIdx.x;
  int rr = tid >> 4;          // 0..15
  int cc = (tid & 15) * 4;    // 0..60
  const float* src = in + (size_t)e * R * C + (size_t)r0 * C + c0;
  #pragma unroll
  for (int rd = 0; rd < 4; ++rd) {
    int r = rd * 16 + rr;
    float4 v = *(const float4*)&src[(size_t)r * C + cc];
    tile[r][cc + 0] = f2bf(v.x);
    tile[r][cc + 1] = f2bf(v.y);
    tile[r][cc + 2] = f2bf(v.z);
    tile[r][cc + 3] = f2bf(v.w);
  }
  __syncthreads();
  u16* dst = out + (size_t)e * R * C + (size_t)c0 * R + r0;
  #pragma unroll
  for (int rd = 0; rd < 4; ++rd) {
    int oc = rd * 16 + rr;    // output row (= input col)
    u16x4 o;
    o[0] = tile[cc + 0][oc];
    o[1] = tile[cc + 1][oc];
    o[2] = tile[cc + 2][oc];
    o[3] = tile[cc + 3][oc];
    *(u16x4*)&dst[(size_t)oc * R + cc] = o;
  }
}

// GEMM1: h[pslot, H] = relu(x[token, D] * w1t[e]^T + b1[e]) -> bf16
// 128x128x32, 2-barrier loop, rule#21 swizzled LDS (src-swizzle + read-XOR)
__global__ __launch_bounds__(256) void gemm1_kernel(
    const u16* __restrict__ xb, const u16* __restrict__ w1t,
    const float* __restrict__ b1, const int* __restrict__ counts,
    const int* __restrict__ poffs, const int* __restrict__ nmb,
    const int* __restrict__ mb2e, const int* __restrict__ mb2m0,
    const int* __restrict__ tlist, u16* __restrict__ hbuf) {
  int mb = blockIdx.x;
  if (mb >= nmb[0]) return;
  int e = mb2e[mb];
  int m0 = mb2m0[mb];
  int ne = counts[e];
  int n0 = blockIdx.y * 128;
  int tid = threadIdx.x;

  __shared__ u16 Als[128 * 32];
  __shared__ u16 Bls[128 * 32];

  int sr = tid >> 2;                           // 0..63 : row within 64-row half
  int sc = (((tid & 3) ^ (sr & 3)) * 8);       // swizzled k-chunk (rule #21: src side)
  const u16* aAdr[2];
  const u16* bAdr[2];
  u16* aLds[2];
  u16* bLds[2];
  #pragma unroll
  for (int r = 0; r < 2; ++r) {
    int tr = m0 + r * 64 + sr;
    int idx = tr < ne ? tr : ne - 1;
    int token = tlist[e * N_TOK + idx] >> 1;
    aAdr[r] = xb + (size_t)token * DIM + sc;
    int nr = n0 + r * 64 + sr;
    bAdr[r] = w1t + ((size_t)e * HID + nr) * DIM + sc;
    aLds[r] = &Als[r * 2048 + tid * 8];
    bLds[r] = &Bls[r * 2048 + tid * 8];
  }

  int lane = tid & 63;
  int wv = tid >> 6;
  int wr = (wv >> 1) * 64, wc = (wv & 1) * 64;
  int fr = lane & 15, fq = lane >> 4;
  int sl = (fq ^ (fr & 3)) * 8;                // swizzled read slot

  f32x4 acc[4][4];
  #pragma unroll
  for (int m = 0; m < 4; ++m)
    #pragma unroll
    for (int n = 0; n < 4; ++n) { f32x4 z = {0.f, 0.f, 0.f, 0.f}; acc[m][n] = z; }

  for (int k0 = 0; k0 < DIM; k0 += 32) {
    __syncthreads();
    gload16(aAdr[0] + k0, aLds[0]);
    gload16(aAdr[1] + k0, aLds[1]);
    gload16(bAdr[0] + k0, bLds[0]);
    gload16(bAdr[1] + k0, bLds[1]);
    __syncthreads();
    s16x8 af[4], bfr[4];
    #pragma unroll
    for (int m = 0; m < 4; ++m)
      af[m] = *(const s16x8*)&Als[(wr + m * 16 + fr) * 32 + sl];
    #pragma unroll
    for (int n = 0; n < 4; ++n)
      bfr[n] = *(const s16x8*)&Bls[(wc + n * 16 + fr) * 32 + sl];
    #pragma unroll
    for (int m = 0; m < 4; ++m)
      #pragma unroll
      for (int n = 0; n < 4; ++n)
        acc[m][n] = __builtin_amdgcn_mfma_f32_16x16x32_bf16(af[m], bfr[n], acc[m][n], 0, 0, 0);
  }

  int pbase = poffs[e] + m0;
  float bias[4];
  #pragma unroll
  for (int n = 0; n < 4; ++n) bias[n] = b1[e * HID + n0 + wc + n * 16 + fr];
  #pragma unroll
  for (int m = 0; m < 4; ++m) {
    #pragma unroll
    for (int j = 0; j < 4; ++j) {
      int row = wr + m * 16 + fq * 4 + j;
      if (m0 + row < ne) {
        u16* hr = hbuf + (size_t)(pbase + row) * HID + n0;
        #pragma unroll
        for (int n = 0; n < 4; ++n) {
          int col = wc + n * 16 + fr;
          float v = acc[m][n][j] + bias[n];
          hr[col] = f2bf(fmaxf(v, 0.f));
        }
      }
    }
  }
}

// GEMM2: y[pslot, D] = h[pslot, H] * w2t[e]^T + b2[e] -> fp32
// 128x128x32, split-K x2 (blockIdx.z), swizzled LDS. z=0 -> yb0 (+bias), z=1 -> yb1.
__global__ __launch_bounds__(256) void gemm2_kernel(
    const u16* __restrict__ hbuf, const u16* __restrict__ w2t,
    const float* __restrict__ b2, const int* __restrict__ counts,
    const int* __restrict__ poffs, const int* __restrict__ nmb,
    const int* __restrict__ mb2e, const int* __restrict__ mb2m0,
    float* __restrict__ yb0, float* __restrict__ yb1) {
  int mb = blockIdx.x;
  if (mb >= nmb[0]) return;
  int e = mb2e[mb];
  int m0 = mb2m0[mb];
  int ne = counts[e];
  int n0 = blockIdx.y * 128;
  int kz = blockIdx.z * (HID / 2);
  int tid = threadIdx.x;
  int pbase = poffs[e] + m0;

  __shared__ u16 Als[128 * 32];
  __shared__ u16 Bls[128 * 32];

  int sr = tid >> 2;
  int sc = (((tid & 3) ^ (sr & 3)) * 8);
  const u16* aAdr[2];
  const u16* bAdr[2];
  u16* aLds[2];
  u16* bLds[2];
  #pragma unroll
  for (int r = 0; r < 2; ++r) {
    int ar = m0 + r * 64 + sr;
    int idx = ar < ne ? ar : ne - 1;
    aAdr[r] = hbuf + (size_t)(poffs[e] + idx) * HID + sc;
    int nr = n0 + r * 64 + sr;
    bAdr[r] = w2t + ((size_t)e * DIM + nr) * HID + sc;
    aLds[r] = &Als[r * 2048 + tid * 8];
    bLds[r] = &Bls[r * 2048 + tid * 8];
  }

  int lane = tid & 63;
  int wv = tid >> 6;
  int wr = (wv >> 1) * 64, wc = (wv & 1) * 64;
  int fr = lane & 15, fq = lane >> 4;
  int sl = (fq ^ (fr & 3)) * 8;

  f32x4 acc[4][4];
  #pragma unroll
  for (int m = 0; m < 4; ++m)
    #pragma unroll
    for (int n = 0; n < 4; ++n) { f32x4 z = {0.f, 0.f, 0.f, 0.f}; acc[m][n] = z; }

  for (int k0 = kz; k0 < kz + HID / 2; k0 += 32) {
    __syncthreads();
    gload16(aAdr[0] + k0, aLds[0]);
    gload16(aAdr[1] + k0, aLds[1]);
    gload16(bAdr[0] + k0, bLds[0]);
    gload16(bAdr[1] + k0, bLds[1]);
    __syncthreads();
    s16x8 af[4], bfr[4];
    #pragma unroll
    for (int m = 0; m < 4; ++m)
      af[m] = *(const s16x8*)&Als[(wr + m * 16 + fr) * 32 + sl];
    #pragma unroll
    for (int n = 0; n < 4; ++n)
      bfr[n] = *(const s16x8*)&Bls[(wc + n * 16 + fr) * 32 + sl];
    #pragma unroll
    for (int m = 0; m < 4; ++m)
      #pragma unroll
      for (int n = 0; n < 4; ++n)
        acc[m][n] = __builtin_amdgcn_mfma_f32_16x16x32_bf16(af[m], bfr[n], acc[m][n], 0, 0, 0);
  }

  float* yb = blockIdx.z ? yb1 : yb0;
  float bias[4];
  #pragma unroll
  for (int n = 0; n < 4; ++n)
    bias[n] = (blockIdx.z == 0) ? b2[e * DIM + n0 + wc + n * 16 + fr] : 0.f;
  #pragma unroll
  for (int m = 0; m < 4; ++m) {
    #pragma unroll
    for (int j = 0; j < 4; ++j) {
      int row = wr + m * 16 + fq * 4 + j;
      if (m0 + row < ne) {
        float* yr = yb + (size_t)(pbase + row) * DIM + n0;
        #pragma unroll
        for (int n = 0; n < 4; ++n) {
          int col = wc + n * 16 + fr;
          yr[col] = acc[m][n][j] + bias[n];
        }
      }
    }
  }
}

__global__ __launch_bounds__(256) void combine_kernel(
    const int* __restrict__ eid, const int* __restrict__ pos,
    const float* __restrict__ wgt, const int* __restrict__ poffs,
    const float* __restrict__ yb0, const float* __restrict__ yb1,
    float* __restrict__ out) {
  int t = blockIdx.x;
  int e0 = eid[2 * t], e1 = eid[2 * t + 1];
  float w0 = wgt[2 * t], w1v = wgt[2 * t + 1];
  size_t g0 = (size_t)(poffs[e0] + pos[2 * t]) * DIM;
  size_t g1 = (size_t)(poffs[e1] + pos[2 * t + 1]) * DIM;
  int d = threadIdx.x * 4;
  float4 a0 = *(const float4*)&yb0[g0 + d];
  float4 a1 = *(const float4*)&yb1[g0 + d];
  float4 b0 = *(const float4*)&yb0[g1 + d];
  float4 b1v = *(const float4*)&yb1[g1 + d];
  float4 o;
  o.x = w0 * (a0.x + a1.x) + w1v * (b0.x + b1v.x);
  o.y = w0 * (a0.y + a1.y) + w1v * (b0.y + b1v.y);
  o.z = w0 * (a0.z + a1.z) + w1v * (b0.z + b1v.z);
  o.w = w0 * (a0.w + a1.w) + w1v * (b0.w + b1v.w);
  *(float4*)&out[(size_t)t * DIM + d] = o;
}

extern "C" void kernel_launch(void* const* d_in, const int* in_sizes, int n_in,
                              void* d_out, int out_size, void* d_ws, size_t ws_size,
                              hipStream_t stream) {
  const float* x  = (const float*)d_in[0];
  const float* gw = (const float*)d_in[1];
  const float* gb = (const float*)d_in[2];
  const float* w1 = (const float*)d_in[3];
  const float* b1 = (const float*)d_in[4];
  const float* w2 = (const float*)d_in[5];
  const float* b2 = (const float*)d_in[6];
  float* out = (float*)d_out;

  char* ws = (char*)d_ws;
  const size_t MB = 1ull << 20;
  // layout: [0,64)   w1t   (dead after gemm1; yb0 36MB aliases here)
  //         [64,128) w2t
  //         [128,136) xb
  //         [136,208) hbuf (9216*4096*2B = 72MB)
  //         [208,244) yb1 (9216*1024*4B = 36MB)
  //         [244,...) meta
  u16*   w1t    = (u16*)(ws);
  float* yb0    = (float*)(ws);              // aliases w1t (dead before gemm2)
  u16*   w2t    = (u16*)(ws + 64 * MB);
  u16*   xb     = (u16*)(ws + 128 * MB);
  u16*   hbuf   = (u16*)(ws + 136 * MB);
  float* yb1    = (float*)(ws + 208 * MB);
  char*  meta   = ws + 244 * MB;
  int*   eid    = (int*)(meta);
  int*   pos    = (int*)(meta + 32 * 1024);
  float* wgt    = (float*)(meta + 64 * 1024);
  int*   counts = (int*)(meta + 96 * 1024);
  int*   offs   = (int*)(meta + 96 * 1024 + 256);
  int*   poffs  = (int*)(meta + 96 * 1024 + 512);
  int*   nmb    = (int*)(meta + 96 * 1024 + 768);
  int*   mb2e   = (int*)(meta + 96 * 1024 + 1024);
  int*   mb2m0  = (int*)(meta + 96 * 1024 + 2048);
  int*   tlist  = (int*)(meta + 128 * 1024);

  init_kernel<<<1, 64, 0, stream>>>(counts);
  gate_kernel<<<N_TOK / 4, 256, 0, stream>>>(x, gw, gb, counts, tlist, eid, pos, wgt);
  scan_kernel<<<1, 64, 0, stream>>>(counts, offs, poffs, nmb, mb2e, mb2m0);
  x2bf_kernel<<<N_TOK * DIM / 1024, 256, 0, stream>>>(x, xb);
  // w1[e][D][H] -> w1t[e][H][D]
  transpose_bf16_kernel<<<dim3(HID / 64, DIM / 64, NE), 256, 0, stream>>>(w1, w1t, DIM, HID);
  // w2[e][H][D] -> w2t[e][D][H]
  transpose_bf16_kernel<<<dim3(DIM / 64, HID / 64, NE), 256, 0, stream>>>(w2, w2t, HID, DIM);
  gemm1_kernel<<<dim3(MAXMB, 32), 256, 0, stream>>>(xb, w1t, b1, counts, poffs, nmb, mb2e, mb2m0, tlist, hbuf);
  gemm2_kernel<<<dim3(MAXMB, 8, 2), 256, 0, stream>>>(hbuf, w2t, b2, counts, poffs, nmb, mb2e, mb2m0, yb0, yb1);
  combine_kernel<<<N_TOK, 256, 0, stream>>>(eid, pos, wgt, poffs, yb0, yb1, out);
}

// Round 7
// 452.036 us; speedup vs baseline: 1.2047x; 1.0163x over previous
//
#include <hip/hip_runtime.h>
#include <hip/hip_bf16.h>

typedef float f32x4 __attribute__((ext_vector_type(4)));
typedef short s16x8 __attribute__((ext_vector_type(8)));
typedef unsigned short u16;
typedef unsigned short u16x4 __attribute__((ext_vector_type(4)));

#define N_TOK 4096
#define DIM 1024
#define HID 4096
#define NE 8
#define MAXMB 72

__device__ __forceinline__ u16 f2bf(float f) {
  unsigned u = __float_as_uint(f);
  u += 0x7fffu + ((u >> 16) & 1u);   // round-to-nearest-even
  return (u16)(u >> 16);
}

__device__ __forceinline__ void gload16(const u16* g, u16* l) {
  __builtin_amdgcn_global_load_lds(
      (const __attribute__((address_space(1))) unsigned int*)g,
      (__attribute__((address_space(3))) unsigned int*)l, 16, 0, 0);
}

__global__ void init_kernel(int* counts) {
  if (threadIdx.x < NE) counts[threadIdx.x] = 0;
}

__global__ __launch_bounds__(256) void gate_kernel(
    const float* __restrict__ x, const float* __restrict__ gw,
    const float* __restrict__ gb, int* __restrict__ counts,
    int* __restrict__ tlist, int* __restrict__ eid, int* __restrict__ pos,
    float* __restrict__ wgt) {
  int t = blockIdx.x * 4 + (threadIdx.x >> 6);
  int lane = threadIdx.x & 63;
  float acc[NE];
  #pragma unroll
  for (int e = 0; e < NE; ++e) acc[e] = 0.f;
  const float* xr = x + (size_t)t * DIM;
  for (int d = lane; d < DIM; d += 64) {
    float xv = xr[d];
    const float* g = gw + d * NE;
    #pragma unroll
    for (int e = 0; e < NE; ++e) acc[e] += xv * g[e];
  }
  #pragma unroll
  for (int off = 32; off > 0; off >>= 1) {
    #pragma unroll
    for (int e = 0; e < NE; ++e) acc[e] += __shfl_down(acc[e], off);
  }
  if (lane == 0) {
    #pragma unroll
    for (int e = 0; e < NE; ++e) acc[e] += gb[e];
    int i0 = 0; float v0 = acc[0];
    #pragma unroll
    for (int e = 1; e < NE; ++e) if (acc[e] > v0) { v0 = acc[e]; i0 = e; }
    int i1 = -1; float v1 = -1e30f;
    #pragma unroll
    for (int e = 0; e < NE; ++e) if (e != i0 && acc[e] > v1) { v1 = acc[e]; i1 = e; }
    float z = expf(v1 - v0);            // v0 >= v1
    float s0 = 1.f / (1.f + z);
    float s1 = z / (1.f + z);
    int p0 = atomicAdd(&counts[i0], 1);
    tlist[i0 * N_TOK + p0] = t * 2 + 0;
    eid[2 * t] = i0; pos[2 * t] = p0; wgt[2 * t] = s0;
    int p1 = atomicAdd(&counts[i1], 1);
    tlist[i1 * N_TOK + p1] = t * 2 + 1;
    eid[2 * t + 1] = i1; pos[2 * t + 1] = p1; wgt[2 * t + 1] = s1;
  }
}

// Builds dense m-block schedule: experts padded to 128-row slot regions.
__global__ void scan_kernel(const int* __restrict__ counts, int* __restrict__ offs,
                            int* __restrict__ poffs, int* __restrict__ nmb,
                            int* __restrict__ mb2e, int* __restrict__ mb2m0) {
  if (threadIdx.x == 0) {
    int s = 0, p = 0, mb = 0;
    for (int e = 0; e < NE; ++e) {
      offs[e] = s; poffs[e] = p;
      int nb = (counts[e] + 127) >> 7;
      for (int i = 0; i < nb; ++i) { mb2e[mb] = e; mb2m0[mb] = i * 128; ++mb; }
      s += counts[e]; p += nb * 128;
    }
    offs[NE] = s; poffs[NE] = p;
    nmb[0] = mb;
    for (int i = mb; i < MAXMB; ++i) { mb2e[i] = 0; mb2m0[i] = 0; }
  }
}

// x (fp32) -> xb (bf16), elementwise
__global__ __launch_bounds__(256) void x2bf_kernel(const float* __restrict__ x,
                                                   u16* __restrict__ xb) {
  int i = (blockIdx.x * 256 + threadIdx.x) * 4;
  float4 v = *(const float4*)&x[i];
  u16x4 o = {f2bf(v.x), f2bf(v.y), f2bf(v.z), f2bf(v.w)};
  *(u16x4*)&xb[i] = o;
}

// in[e][R][C] fp32 -> out[e][C][R] bf16 (64x64 LDS tile transpose)
__global__ __launch_bounds__(256) void transpose_bf16_kernel(
    const float* __restrict__ in, u16* __restrict__ out, int R, int C) {
  __shared__ u16 tile[64][65];
  int e = blockIdx.z;
  int c0 = blockIdx.x * 64, r0 = blockIdx.y * 64;
  int tid = threadIdx.x;
  int rr = tid >> 4;          // 0..15
  int cc = (tid & 15) * 4;    // 0..60
  const float* src = in + (size_t)e * R * C + (size_t)r0 * C + c0;
  #pragma unroll
  for (int rd = 0; rd < 4; ++rd) {
    int r = rd * 16 + rr;
    float4 v = *(const float4*)&src[(size_t)r * C + cc];
    tile[r][cc + 0] = f2bf(v.x);
    tile[r][cc + 1] = f2bf(v.y);
    tile[r][cc + 2] = f2bf(v.z);
    tile[r][cc + 3] = f2bf(v.w);
  }
  __syncthreads();
  u16* dst = out + (size_t)e * R * C + (size_t)c0 * R + r0;
  #pragma unroll
  for (int rd = 0; rd < 4; ++rd) {
    int oc = rd * 16 + rr;    // output row (= input col)
    u16x4 o;
    o[0] = tile[cc + 0][oc];
    o[1] = tile[cc + 1][oc];
    o[2] = tile[cc + 2][oc];
    o[3] = tile[cc + 3][oc];
    *(u16x4*)&dst[(size_t)oc * R + cc] = o;
  }
}

// GEMM1: h[pslot, H] = relu(x[token, D] * w1t[e]^T + b1[e]) -> bf16
// 128x128x64, 2-barrier loop, T2 XOR swizzle (global-src pre-swizzle + read XOR)
// grid: (n-blocks fastest, mb) for A-panel L2 adjacency
__global__ __launch_bounds__(256) void gemm1_kernel(
    const u16* __restrict__ xb, const u16* __restrict__ w1t,
    const float* __restrict__ b1, const int* __restrict__ counts,
    const int* __restrict__ poffs, const int* __restrict__ nmb,
    const int* __restrict__ mb2e, const int* __restrict__ mb2m0,
    const int* __restrict__ tlist, u16* __restrict__ hbuf) {
  int mb = blockIdx.y;
  if (mb >= nmb[0]) return;
  int e = mb2e[mb];
  int m0 = mb2m0[mb];
  int ne = counts[e];
  int n0 = blockIdx.x * 128;
  int tid = threadIdx.x;

  __shared__ u16 Als[128 * 64];
  __shared__ u16 Bls[128 * 64];

  int rsub = tid >> 3;                          // 0..31 row sub-index
  int kch  = ((tid & 7) ^ (rsub & 7)) * 8;      // pre-swizzled source chunk (u16)
  const u16* aSrc[4];
  const u16* bSrc[4];
  #pragma unroll
  for (int j = 0; j < 4; ++j) {
    int r = m0 + j * 32 + rsub;
    int idx = r < ne ? r : ne - 1;
    aSrc[j] = xb + (size_t)(tlist[e * N_TOK + idx] >> 1) * DIM + kch;
    bSrc[j] = w1t + ((size_t)e * HID + n0 + j * 32 + rsub) * DIM + kch;
  }

  int lane = tid & 63;
  int wv = tid >> 6;
  int wr = (wv >> 1) * 64, wc = (wv & 1) * 64;
  int fr = lane & 15, fq = lane >> 4;

  f32x4 acc[4][4];
  #pragma unroll
  for (int m = 0; m < 4; ++m)
    #pragma unroll
    for (int n = 0; n < 4; ++n) { f32x4 z = {0.f, 0.f, 0.f, 0.f}; acc[m][n] = z; }

  for (int k0 = 0; k0 < DIM; k0 += 64) {
    __syncthreads();
    #pragma unroll
    for (int j = 0; j < 4; ++j) {
      gload16(aSrc[j] + k0, &Als[j * 2048 + tid * 8]);
      gload16(bSrc[j] + k0, &Bls[j * 2048 + tid * 8]);
    }
    __syncthreads();
    #pragma unroll
    for (int t = 0; t < 2; ++t) {
      s16x8 af[4], bf_[4];
      #pragma unroll
      for (int m = 0; m < 4; ++m) {
        int row = wr + m * 16 + fr;
        af[m] = *(const s16x8*)&Als[row * 64 + (((t * 4 + fq) ^ (row & 7)) * 8)];
      }
      #pragma unroll
      for (int n = 0; n < 4; ++n) {
        int row = wc + n * 16 + fr;
        bf_[n] = *(const s16x8*)&Bls[row * 64 + (((t * 4 + fq) ^ (row & 7)) * 8)];
      }
      #pragma unroll
      for (int m = 0; m < 4; ++m)
        #pragma unroll
        for (int n = 0; n < 4; ++n)
          acc[m][n] = __builtin_amdgcn_mfma_f32_16x16x32_bf16(af[m], bf_[n], acc[m][n], 0, 0, 0);
    }
  }

  int pbase = poffs[e] + m0;
  float bias[4];
  #pragma unroll
  for (int n = 0; n < 4; ++n) bias[n] = b1[e * HID + n0 + wc + n * 16 + fr];
  #pragma unroll
  for (int m = 0; m < 4; ++m) {
    #pragma unroll
    for (int j = 0; j < 4; ++j) {
      int row = wr + m * 16 + fq * 4 + j;
      if (m0 + row < ne) {
        u16* hr = hbuf + (size_t)(pbase + row) * HID + n0;
        #pragma unroll
        for (int n = 0; n < 4; ++n) {
          int col = wc + n * 16 + fr;
          float v = acc[m][n][j] + bias[n];
          hr[col] = f2bf(fmaxf(v, 0.f));
        }
      }
    }
  }
}

// GEMM2: y[pslot, D] = h[pslot, H] * w2t[e]^T + b2[e] -> fp32
// 128x128x64, split-K x2, T2 swizzle, grid (n-blocks fastest, mb, z)
__global__ __launch_bounds__(256) void gemm2_kernel(
    const u16* __restrict__ hbuf, const u16* __restrict__ w2t,
    const float* __restrict__ b2, const int* __restrict__ counts,
    const int* __restrict__ poffs, const int* __restrict__ nmb,
    const int* __restrict__ mb2e, const int* __restrict__ mb2m0,
    float* __restrict__ yb0, float* __restrict__ yb1) {
  int mb = blockIdx.y;
  if (mb >= nmb[0]) return;
  int e = mb2e[mb];
  int m0 = mb2m0[mb];
  int ne = counts[e];
  int n0 = blockIdx.x * 128;
  int kz = blockIdx.z * (HID / 2);
  int tid = threadIdx.x;
  int pbase = poffs[e] + m0;

  __shared__ u16 Als[128 * 64];
  __shared__ u16 Bls[128 * 64];

  int rsub = tid >> 3;
  int kch  = ((tid & 7) ^ (rsub & 7)) * 8;
  const u16* aSrc[4];
  const u16* bSrc[4];
  #pragma unroll
  for (int j = 0; j < 4; ++j) {
    int r = m0 + j * 32 + rsub;
    int idx = r < ne ? r : ne - 1;
    aSrc[j] = hbuf + (size_t)(poffs[e] + idx) * HID + kz + kch;
    bSrc[j] = w2t + ((size_t)e * DIM + n0 + j * 32 + rsub) * HID + kz + kch;
  }

  int lane = tid & 63;
  int wv = tid >> 6;
  int wr = (wv >> 1) * 64, wc = (wv & 1) * 64;
  int fr = lane & 15, fq = lane >> 4;

  f32x4 acc[4][4];
  #pragma unroll
  for (int m = 0; m < 4; ++m)
    #pragma unroll
    for (int n = 0; n < 4; ++n) { f32x4 z = {0.f, 0.f, 0.f, 0.f}; acc[m][n] = z; }

  for (int k0 = 0; k0 < HID / 2; k0 += 64) {
    __syncthreads();
    #pragma unroll
    for (int j = 0; j < 4; ++j) {
      gload16(aSrc[j] + k0, &Als[j * 2048 + tid * 8]);
      gload16(bSrc[j] + k0, &Bls[j * 2048 + tid * 8]);
    }
    __syncthreads();
    #pragma unroll
    for (int t = 0; t < 2; ++t) {
      s16x8 af[4], bf_[4];
      #pragma unroll
      for (int m = 0; m < 4; ++m) {
        int row = wr + m * 16 + fr;
        af[m] = *(const s16x8*)&Als[row * 64 + (((t * 4 + fq) ^ (row & 7)) * 8)];
      }
      #pragma unroll
      for (int n = 0; n < 4; ++n) {
        int row = wc + n * 16 + fr;
        bf_[n] = *(const s16x8*)&Bls[row * 64 + (((t * 4 + fq) ^ (row & 7)) * 8)];
      }
      #pragma unroll
      for (int m = 0; m < 4; ++m)
        #pragma unroll
        for (int n = 0; n < 4; ++n)
          acc[m][n] = __builtin_amdgcn_mfma_f32_16x16x32_bf16(af[m], bf_[n], acc[m][n], 0, 0, 0);
    }
  }

  float* yb = blockIdx.z ? yb1 : yb0;
  float bias[4];
  #pragma unroll
  for (int n = 0; n < 4; ++n)
    bias[n] = (blockIdx.z == 0) ? b2[e * DIM + n0 + wc + n * 16 + fr] : 0.f;
  #pragma unroll
  for (int m = 0; m < 4; ++m) {
    #pragma unroll
    for (int j = 0; j < 4; ++j) {
      int row = wr + m * 16 + fq * 4 + j;
      if (m0 + row < ne) {
        float* yr = yb + (size_t)(pbase + row) * DIM + n0;
        #pragma unroll
        for (int n = 0; n < 4; ++n) {
          int col = wc + n * 16 + fr;
          yr[col] = acc[m][n][j] + bias[n];
        }
      }
    }
  }
}

__global__ __launch_bounds__(256) void combine_kernel(
    const int* __restrict__ eid, const int* __restrict__ pos,
    const float* __restrict__ wgt, const int* __restrict__ poffs,
    const float* __restrict__ yb0, const float* __restrict__ yb1,
    float* __restrict__ out) {
  int t = blockIdx.x;
  int e0 = eid[2 * t], e1 = eid[2 * t + 1];
  float w0 = wgt[2 * t], w1v = wgt[2 * t + 1];
  size_t g0 = (size_t)(poffs[e0] + pos[2 * t]) * DIM;
  size_t g1 = (size_t)(poffs[e1] + pos[2 * t + 1]) * DIM;
  int d = threadIdx.x * 4;
  float4 a0 = *(const float4*)&yb0[g0 + d];
  float4 a1 = *(const float4*)&yb1[g0 + d];
  float4 b0 = *(const float4*)&yb0[g1 + d];
  float4 b1v = *(const float4*)&yb1[g1 + d];
  float4 o;
  o.x = w0 * (a0.x + a1.x) + w1v * (b0.x + b1v.x);
  o.y = w0 * (a0.y + a1.y) + w1v * (b0.y + b1v.y);
  o.z = w0 * (a0.z + a1.z) + w1v * (b0.z + b1v.z);
  o.w = w0 * (a0.w + a1.w) + w1v * (b0.w + b1v.w);
  *(float4*)&out[(size_t)t * DIM + d] = o;
}

extern "C" void kernel_launch(void* const* d_in, const int* in_sizes, int n_in,
                              void* d_out, int out_size, void* d_ws, size_t ws_size,
                              hipStream_t stream) {
  const float* x  = (const float*)d_in[0];
  const float* gw = (const float*)d_in[1];
  const float* gb = (const float*)d_in[2];
  const float* w1 = (const float*)d_in[3];
  const float* b1 = (const float*)d_in[4];
  const float* w2 = (const float*)d_in[5];
  const float* b2 = (const float*)d_in[6];
  float* out = (float*)d_out;

  char* ws = (char*)d_ws;
  const size_t MB = 1ull << 20;
  // layout: [0,64)   w1t   (dead after gemm1; yb0 36MB aliases here)
  //         [64,128) w2t
  //         [128,136) xb
  //         [136,208) hbuf (9216*4096*2B = 72MB)
  //         [208,244) yb1 (9216*1024*4B = 36MB)
  //         [244,...) meta
  u16*   w1t    = (u16*)(ws);
  float* yb0    = (float*)(ws);              // aliases w1t (dead before gemm2)
  u16*   w2t    = (u16*)(ws + 64 * MB);
  u16*   xb     = (u16*)(ws + 128 * MB);
  u16*   hbuf   = (u16*)(ws + 136 * MB);
  float* yb1    = (float*)(ws + 208 * MB);
  char*  meta   = ws + 244 * MB;
  int*   eid    = (int*)(meta);
  int*   pos    = (int*)(meta + 32 * 1024);
  float* wgt    = (float*)(meta + 64 * 1024);
  int*   counts = (int*)(meta + 96 * 1024);
  int*   offs   = (int*)(meta + 96 * 1024 + 256);
  int*   poffs  = (int*)(meta + 96 * 1024 + 512);
  int*   nmb    = (int*)(meta + 96 * 1024 + 768);
  int*   mb2e   = (int*)(meta + 96 * 1024 + 1024);
  int*   mb2m0  = (int*)(meta + 96 * 1024 + 2048);
  int*   tlist  = (int*)(meta + 128 * 1024);

  init_kernel<<<1, 64, 0, stream>>>(counts);
  gate_kernel<<<N_TOK / 4, 256, 0, stream>>>(x, gw, gb, counts, tlist, eid, pos, wgt);
  scan_kernel<<<1, 64, 0, stream>>>(counts, offs, poffs, nmb, mb2e, mb2m0);
  x2bf_kernel<<<N_TOK * DIM / 1024, 256, 0, stream>>>(x, xb);
  // w1[e][D][H] -> w1t[e][H][D]
  transpose_bf16_kernel<<<dim3(HID / 64, DIM / 64, NE), 256, 0, stream>>>(w1, w1t, DIM, HID);
  // w2[e][H][D] -> w2t[e][D][H]
  transpose_bf16_kernel<<<dim3(DIM / 64, HID / 64, NE), 256, 0, stream>>>(w2, w2t, HID, DIM);
  gemm1_kernel<<<dim3(32, MAXMB), 256, 0, stream>>>(xb, w1t, b1, counts, poffs, nmb, mb2e, mb2m0, tlist, hbuf);
  gemm2_kernel<<<dim3(8, MAXMB, 2), 256, 0, stream>>>(hbuf, w2t, b2, counts, poffs, nmb, mb2e, mb2m0, yb0, yb1);
  combine_kernel<<<N_TOK, 256, 0, stream>>>(eid, pos, wgt, poffs, yb0, yb1, out);
}

// Round 8
// 419.399 us; speedup vs baseline: 1.2985x; 1.0778x over previous
//
#include <hip/hip_runtime.h>
#include <hip/hip_bf16.h>

typedef float f32x4 __attribute__((ext_vector_type(4)));
typedef short s16x8 __attribute__((ext_vector_type(8)));
typedef unsigned short u16;
typedef unsigned short u16x4 __attribute__((ext_vector_type(4)));

#define N_TOK 4096
#define DIM 1024
#define HID 4096
#define NE 8
#define MAXMB 72

#define WAITV(n) asm volatile("s_waitcnt vmcnt(" #n ")" ::: "memory")

__device__ __forceinline__ void wgbar() {
  asm volatile("" ::: "memory");
  __builtin_amdgcn_s_barrier();
  asm volatile("" ::: "memory");
}

__device__ __forceinline__ u16 f2bf(float f) {
  unsigned u = __float_as_uint(f);
  u += 0x7fffu + ((u >> 16) & 1u);   // round-to-nearest-even
  return (u16)(u >> 16);
}

__device__ __forceinline__ void gload16(const u16* g, u16* l) {
  __builtin_amdgcn_global_load_lds(
      (const __attribute__((address_space(1))) unsigned int*)g,
      (__attribute__((address_space(3))) unsigned int*)l, 16, 0, 0);
}

__global__ void init_kernel(int* counts) {
  if (threadIdx.x < NE) counts[threadIdx.x] = 0;
}

// gate + x->bf16 conversion fused (gate already reads every x element)
__global__ __launch_bounds__(256) void gate_kernel(
    const float* __restrict__ x, const float* __restrict__ gw,
    const float* __restrict__ gb, int* __restrict__ counts,
    int* __restrict__ tlist, int* __restrict__ eid, int* __restrict__ pos,
    float* __restrict__ wgt, u16* __restrict__ xb) {
  int t = blockIdx.x * 4 + (threadIdx.x >> 6);
  int lane = threadIdx.x & 63;
  float acc[NE];
  #pragma unroll
  for (int e = 0; e < NE; ++e) acc[e] = 0.f;
  const float* xr = x + (size_t)t * DIM;
  u16* xbr = xb + (size_t)t * DIM;
  for (int d = lane; d < DIM; d += 64) {
    float xv = xr[d];
    xbr[d] = f2bf(xv);
    const float* g = gw + d * NE;
    #pragma unroll
    for (int e = 0; e < NE; ++e) acc[e] += xv * g[e];
  }
  #pragma unroll
  for (int off = 32; off > 0; off >>= 1) {
    #pragma unroll
    for (int e = 0; e < NE; ++e) acc[e] += __shfl_down(acc[e], off);
  }
  if (lane == 0) {
    #pragma unroll
    for (int e = 0; e < NE; ++e) acc[e] += gb[e];
    int i0 = 0; float v0 = acc[0];
    #pragma unroll
    for (int e = 1; e < NE; ++e) if (acc[e] > v0) { v0 = acc[e]; i0 = e; }
    int i1 = -1; float v1 = -1e30f;
    #pragma unroll
    for (int e = 0; e < NE; ++e) if (e != i0 && acc[e] > v1) { v1 = acc[e]; i1 = e; }
    float z = expf(v1 - v0);            // v0 >= v1
    float s0 = 1.f / (1.f + z);
    float s1 = z / (1.f + z);
    int p0 = atomicAdd(&counts[i0], 1);
    tlist[i0 * N_TOK + p0] = t * 2 + 0;
    eid[2 * t] = i0; pos[2 * t] = p0; wgt[2 * t] = s0;
    int p1 = atomicAdd(&counts[i1], 1);
    tlist[i1 * N_TOK + p1] = t * 2 + 1;
    eid[2 * t + 1] = i1; pos[2 * t + 1] = p1; wgt[2 * t + 1] = s1;
  }
}

// Builds dense m-block schedule: experts padded to 128-row slot regions.
__global__ void scan_kernel(const int* __restrict__ counts, int* __restrict__ offs,
                            int* __restrict__ poffs, int* __restrict__ nmb,
                            int* __restrict__ mb2e, int* __restrict__ mb2m0) {
  if (threadIdx.x == 0) {
    int s = 0, p = 0, mb = 0;
    for (int e = 0; e < NE; ++e) {
      offs[e] = s; poffs[e] = p;
      int nb = (counts[e] + 127) >> 7;
      for (int i = 0; i < nb; ++i) { mb2e[mb] = e; mb2m0[mb] = i * 128; ++mb; }
      s += counts[e]; p += nb * 128;
    }
    offs[NE] = s; poffs[NE] = p;
    nmb[0] = mb;
    for (int i = mb; i < MAXMB; ++i) { mb2e[i] = 0; mb2m0[i] = 0; }
  }
}

// Both weight transposes in one launch. bid<8192: w1[e][D][H]->w1t[e][H][D];
// else w2[e][H][D]->w2t[e][D][H]. 1024 64x64 tiles per expert either way.
__global__ __launch_bounds__(256) void transpose_all_kernel(
    const float* __restrict__ w1, const float* __restrict__ w2,
    u16* __restrict__ w1t, u16* __restrict__ w2t) {
  __shared__ u16 tile[64][65];
  int bid = blockIdx.x;
  const float* in; u16* out; int R, C, csh, rem;
  if (bid < 8192) { in = w1; out = w1t; R = DIM; C = HID; csh = 6; rem = bid; }
  else           { in = w2; out = w2t; R = HID; C = DIM; csh = 4; rem = bid - 8192; }
  int e = rem >> 10;
  int r2 = rem & 1023;
  int rt = r2 >> csh;
  int ct = r2 & ((1 << csh) - 1);
  int r0 = rt * 64, c0 = ct * 64;
  int tid = threadIdx.x;
  int rr = tid >> 4;          // 0..15
  int cc = (tid & 15) * 4;    // 0..60
  const float* src = in + (size_t)e * R * C + (size_t)r0 * C + c0;
  #pragma unroll
  for (int rd = 0; rd < 4; ++rd) {
    int r = rd * 16 + rr;
    float4 v = *(const float4*)&src[(size_t)r * C + cc];
    tile[r][cc + 0] = f2bf(v.x);
    tile[r][cc + 1] = f2bf(v.y);
    tile[r][cc + 2] = f2bf(v.z);
    tile[r][cc + 3] = f2bf(v.w);
  }
  __syncthreads();
  u16* dst = out + (size_t)e * R * C + (size_t)c0 * R + r0;
  #pragma unroll
  for (int rd = 0; rd < 4; ++rd) {
    int oc = rd * 16 + rr;    // output row (= input col)
    u16x4 o;
    o[0] = tile[cc + 0][oc];
    o[1] = tile[cc + 1][oc];
    o[2] = tile[cc + 2][oc];
    o[3] = tile[cc + 3][oc];
    *(u16x4*)&dst[(size_t)oc * R + cc] = o;
  }
}

// GEMM1: h[pslot, H] = relu(x[token, D] * w1t[e]^T + b1[e]) -> bf16
// 128x128, BK=32, 3-stage LDS pipeline, counted vmcnt (T3+T4), raw s_barrier.
// LDS slot swizzle: slot = chunk ^ (row&3) ^ ((row>>2)&3)  -> 2-way (free).
__global__ __launch_bounds__(256) void gemm1_kernel(
    const u16* __restrict__ xb, const u16* __restrict__ w1t,
    const float* __restrict__ b1, const int* __restrict__ counts,
    const int* __restrict__ poffs, const int* __restrict__ nmb,
    const int* __restrict__ mb2e, const int* __restrict__ mb2m0,
    const int* __restrict__ tlist, u16* __restrict__ hbuf) {
  int mb = blockIdx.y;
  if (mb >= nmb[0]) return;
  int e = mb2e[mb];
  int m0 = mb2m0[mb];
  int ne = counts[e];
  int n0 = blockIdx.x * 128;
  int tid = threadIdx.x;

  __shared__ u16 lds[24576];        // A: 3 x 4096 u16 | B: 3 x 4096 u16
  u16* Al = lds;
  u16* Bl = lds + 12288;

  const u16* aS0; const u16* aS1; const u16* bS0; const u16* bS1;
  int ld0, ld1;
  {
    int c = tid;
    int row = c >> 2, slot = c & 3;
    int ksl = slot ^ (row & 3) ^ ((row >> 2) & 3);
    ld0 = c * 8;
    int r = m0 + row; int idx = r < ne ? r : ne - 1;
    aS0 = xb + (size_t)(tlist[e * N_TOK + idx] >> 1) * DIM + ksl * 8;
    bS0 = w1t + ((size_t)e * HID + n0 + row) * DIM + ksl * 8;
    c = tid + 256;
    row = c >> 2; slot = c & 3;
    ksl = slot ^ (row & 3) ^ ((row >> 2) & 3);
    ld1 = c * 8;
    r = m0 + row; idx = r < ne ? r : ne - 1;
    aS1 = xb + (size_t)(tlist[e * N_TOK + idx] >> 1) * DIM + ksl * 8;
    bS1 = w1t + ((size_t)e * HID + n0 + row) * DIM + ksl * 8;
  }

#define STG1(kk, s) do { \
    gload16(aS0 + (kk), &Al[(s) * 4096 + ld0]); \
    gload16(aS1 + (kk), &Al[(s) * 4096 + ld1]); \
    gload16(bS0 + (kk), &Bl[(s) * 4096 + ld0]); \
    gload16(bS1 + (kk), &Bl[(s) * 4096 + ld1]); } while (0)

  int lane = tid & 63;
  int wv = tid >> 6;
  int wr = (wv >> 1) * 64, wc = (wv & 1) * 64;
  int fr = lane & 15, fq = lane >> 4;
  int soff = (fq ^ (fr & 3) ^ ((fr >> 2) & 3)) * 8;

  f32x4 acc[4][4];
  #pragma unroll
  for (int m = 0; m < 4; ++m)
    #pragma unroll
    for (int n = 0; n < 4; ++n) { f32x4 z = {0.f, 0.f, 0.f, 0.f}; acc[m][n] = z; }

  STG1(0, 0);
  STG1(32, 1);
  int st = 0, pst = 2;
  for (int t = 0; t < 32; ++t) {
    if (t < 30)      { STG1((t + 2) * 32, pst); WAITV(8); }
    else if (t == 30) { WAITV(4); }
    else              { WAITV(0); }
    wgbar();
    {
      const u16* Ab = &Al[st * 4096];
      const u16* Bb = &Bl[st * 4096];
      s16x8 af[4], bf_[4];
      #pragma unroll
      for (int m = 0; m < 4; ++m)
        af[m] = *(const s16x8*)&Ab[(wr + m * 16 + fr) * 32 + soff];
      #pragma unroll
      for (int n = 0; n < 4; ++n)
        bf_[n] = *(const s16x8*)&Bb[(wc + n * 16 + fr) * 32 + soff];
      #pragma unroll
      for (int m = 0; m < 4; ++m)
        #pragma unroll
        for (int n = 0; n < 4; ++n)
          acc[m][n] = __builtin_amdgcn_mfma_f32_16x16x32_bf16(af[m], bf_[n], acc[m][n], 0, 0, 0);
    }
    wgbar();
    st = st == 2 ? 0 : st + 1;
    pst = pst == 2 ? 0 : pst + 1;
  }
#undef STG1

  int pbase = poffs[e] + m0;
  float bias[4];
  #pragma unroll
  for (int n = 0; n < 4; ++n) bias[n] = b1[e * HID + n0 + wc + n * 16 + fr];
  #pragma unroll
  for (int m = 0; m < 4; ++m) {
    #pragma unroll
    for (int j = 0; j < 4; ++j) {
      int row = wr + m * 16 + fq * 4 + j;
      if (m0 + row < ne) {
        u16* hr = hbuf + (size_t)(pbase + row) * HID + n0;
        #pragma unroll
        for (int n = 0; n < 4; ++n) {
          int col = wc + n * 16 + fr;
          float v = acc[m][n][j] + bias[n];
          hr[col] = f2bf(fmaxf(v, 0.f));
        }
      }
    }
  }
}

// GEMM2: y[pslot, D] = h[pslot, H] * w2t[e]^T + b2[e] -> fp32
// same pipeline; split-K x2 (blockIdx.z), NT=64 steps of 32.
__global__ __launch_bounds__(256) void gemm2_kernel(
    const u16* __restrict__ hbuf, const u16* __restrict__ w2t,
    const float* __restrict__ b2, const int* __restrict__ counts,
    const int* __restrict__ poffs, const int* __restrict__ nmb,
    const int* __restrict__ mb2e, const int* __restrict__ mb2m0,
    float* __restrict__ yb0, float* __restrict__ yb1) {
  int mb = blockIdx.y;
  if (mb >= nmb[0]) return;
  int e = mb2e[mb];
  int m0 = mb2m0[mb];
  int ne = counts[e];
  int n0 = blockIdx.x * 128;
  int kz = blockIdx.z * (HID / 2);
  int tid = threadIdx.x;
  int pbase = poffs[e] + m0;

  __shared__ u16 lds[24576];
  u16* Al = lds;
  u16* Bl = lds + 12288;

  const u16* aS0; const u16* aS1; const u16* bS0; const u16* bS1;
  int ld0, ld1;
  {
    int c = tid;
    int row = c >> 2, slot = c & 3;
    int ksl = slot ^ (row & 3) ^ ((row >> 2) & 3);
    ld0 = c * 8;
    int r = m0 + row; int idx = r < ne ? r : ne - 1;
    aS0 = hbuf + (size_t)(poffs[e] + idx) * HID + kz + ksl * 8;
    bS0 = w2t + ((size_t)e * DIM + n0 + row) * HID + kz + ksl * 8;
    c = tid + 256;
    row = c >> 2; slot = c & 3;
    ksl = slot ^ (row & 3) ^ ((row >> 2) & 3);
    ld1 = c * 8;
    r = m0 + row; idx = r < ne ? r : ne - 1;
    aS1 = hbuf + (size_t)(poffs[e] + idx) * HID + kz + ksl * 8;
    bS1 = w2t + ((size_t)e * DIM + n0 + row) * HID + kz + ksl * 8;
  }

#define STG2(kk, s) do { \
    gload16(aS0 + (kk), &Al[(s) * 4096 + ld0]); \
    gload16(aS1 + (kk), &Al[(s) * 4096 + ld1]); \
    gload16(bS0 + (kk), &Bl[(s) * 4096 + ld0]); \
    gload16(bS1 + (kk), &Bl[(s) * 4096 + ld1]); } while (0)

  int lane = tid & 63;
  int wv = tid >> 6;
  int wr = (wv >> 1) * 64, wc = (wv & 1) * 64;
  int fr = lane & 15, fq = lane >> 4;
  int soff = (fq ^ (fr & 3) ^ ((fr >> 2) & 3)) * 8;

  f32x4 acc[4][4];
  #pragma unroll
  for (int m = 0; m < 4; ++m)
    #pragma unroll
    for (int n = 0; n < 4; ++n) { f32x4 z = {0.f, 0.f, 0.f, 0.f}; acc[m][n] = z; }

  STG2(0, 0);
  STG2(32, 1);
  int st = 0, pst = 2;
  for (int t = 0; t < 64; ++t) {
    if (t < 62)      { STG2((t + 2) * 32, pst); WAITV(8); }
    else if (t == 62) { WAITV(4); }
    else              { WAITV(0); }
    wgbar();
    {
      const u16* Ab = &Al[st * 4096];
      const u16* Bb = &Bl[st * 4096];
      s16x8 af[4], bf_[4];
      #pragma unroll
      for (int m = 0; m < 4; ++m)
        af[m] = *(const s16x8*)&Ab[(wr + m * 16 + fr) * 32 + soff];
      #pragma unroll
      for (int n = 0; n < 4; ++n)
        bf_[n] = *(const s16x8*)&Bb[(wc + n * 16 + fr) * 32 + soff];
      #pragma unroll
      for (int m = 0; m < 4; ++m)
        #pragma unroll
        for (int n = 0; n < 4; ++n)
          acc[m][n] = __builtin_amdgcn_mfma_f32_16x16x32_bf16(af[m], bf_[n], acc[m][n], 0, 0, 0);
    }
    wgbar();
    st = st == 2 ? 0 : st + 1;
    pst = pst == 2 ? 0 : pst + 1;
  }
#undef STG2

  float* yb = blockIdx.z ? yb1 : yb0;
  float bias[4];
  #pragma unroll
  for (int n = 0; n < 4; ++n)
    bias[n] = (blockIdx.z == 0) ? b2[e * DIM + n0 + wc + n * 16 + fr] : 0.f;
  #pragma unroll
  for (int m = 0; m < 4; ++m) {
    #pragma unroll
    for (int j = 0; j < 4; ++j) {
      int row = wr + m * 16 + fq * 4 + j;
      if (m0 + row < ne) {
        float* yr = yb + (size_t)(pbase + row) * DIM + n0;
        #pragma unroll
        for (int n = 0; n < 4; ++n) {
          int col = wc + n * 16 + fr;
          yr[col] = acc[m][n][j] + bias[n];
        }
      }
    }
  }
}

__global__ __launch_bounds__(256) void combine_kernel(
    const int* __restrict__ eid, const int* __restrict__ pos,
    const float* __restrict__ wgt, const int* __restrict__ poffs,
    const float* __restrict__ yb0, const float* __restrict__ yb1,
    float* __restrict__ out) {
  int t = blockIdx.x;
  int e0 = eid[2 * t], e1 = eid[2 * t + 1];
  float w0 = wgt[2 * t], w1v = wgt[2 * t + 1];
  size_t g0 = (size_t)(poffs[e0] + pos[2 * t]) * DIM;
  size_t g1 = (size_t)(poffs[e1] + pos[2 * t + 1]) * DIM;
  int d = threadIdx.x * 4;
  float4 a0 = *(const float4*)&yb0[g0 + d];
  float4 a1 = *(const float4*)&yb1[g0 + d];
  float4 b0 = *(const float4*)&yb0[g1 + d];
  float4 b1v = *(const float4*)&yb1[g1 + d];
  float4 o;
  o.x = w0 * (a0.x + a1.x) + w1v * (b0.x + b1v.x);
  o.y = w0 * (a0.y + a1.y) + w1v * (b0.y + b1v.y);
  o.z = w0 * (a0.z + a1.z) + w1v * (b0.z + b1v.z);
  o.w = w0 * (a0.w + a1.w) + w1v * (b0.w + b1v.w);
  *(float4*)&out[(size_t)t * DIM + d] = o;
}

extern "C" void kernel_launch(void* const* d_in, const int* in_sizes, int n_in,
                              void* d_out, int out_size, void* d_ws, size_t ws_size,
                              hipStream_t stream) {
  const float* x  = (const float*)d_in[0];
  const float* gw = (const float*)d_in[1];
  const float* gb = (const float*)d_in[2];
  const float* w1 = (const float*)d_in[3];
  const float* b1 = (const float*)d_in[4];
  const float* w2 = (const float*)d_in[5];
  const float* b2 = (const float*)d_in[6];
  float* out = (float*)d_out;

  char* ws = (char*)d_ws;
  const size_t MB = 1ull << 20;
  // layout: [0,64)   w1t   (dead after gemm1; yb0 36MB aliases here)
  //         [64,128) w2t
  //         [128,136) xb
  //         [136,208) hbuf (9216*4096*2B = 72MB)
  //         [208,244) yb1 (9216*1024*4B = 36MB)
  //         [244,...) meta
  u16*   w1t    = (u16*)(ws);
  float* yb0    = (float*)(ws);              // aliases w1t (dead before gemm2)
  u16*   w2t    = (u16*)(ws + 64 * MB);
  u16*   xb     = (u16*)(ws + 128 * MB);
  u16*   hbuf   = (u16*)(ws + 136 * MB);
  float* yb1    = (float*)(ws + 208 * MB);
  char*  meta   = ws + 244 * MB;
  int*   eid    = (int*)(meta);
  int*   pos    = (int*)(meta + 32 * 1024);
  float* wgt    = (float*)(meta + 64 * 1024);
  int*   counts = (int*)(meta + 96 * 1024);
  int*   offs   = (int*)(meta + 96 * 1024 + 256);
  int*   poffs  = (int*)(meta + 96 * 1024 + 512);
  int*   nmb    = (int*)(meta + 96 * 1024 + 768);
  int*   mb2e   = (int*)(meta + 96 * 1024 + 1024);
  int*   mb2m0  = (int*)(meta + 96 * 1024 + 2048);
  int*   tlist  = (int*)(meta + 128 * 1024);

  init_kernel<<<1, 64, 0, stream>>>(counts);
  gate_kernel<<<N_TOK / 4, 256, 0, stream>>>(x, gw, gb, counts, tlist, eid, pos, wgt, xb);
  scan_kernel<<<1, 64, 0, stream>>>(counts, offs, poffs, nmb, mb2e, mb2m0);
  transpose_all_kernel<<<16384, 256, 0, stream>>>(w1, w2, w1t, w2t);
  gemm1_kernel<<<dim3(32, MAXMB), 256, 0, stream>>>(xb, w1t, b1, counts, poffs, nmb, mb2e, mb2m0, tlist, hbuf);
  gemm2_kernel<<<dim3(8, MAXMB, 2), 256, 0, stream>>>(hbuf, w2t, b2, counts, poffs, nmb, mb2e, mb2m0, yb0, yb1);
  combine_kernel<<<N_TOK, 256, 0, stream>>>(eid, pos, wgt, poffs, yb0, yb1, out);
}

// Round 9
// 405.551 us; speedup vs baseline: 1.3428x; 1.0341x over previous
//
#include <hip/hip_runtime.h>
#include <hip/hip_bf16.h>

typedef float f32x4 __attribute__((ext_vector_type(4)));
typedef short s16x8 __attribute__((ext_vector_type(8)));
typedef unsigned short u16;
typedef unsigned short u16x4 __attribute__((ext_vector_type(4)));

#define N_TOK 4096
#define DIM 1024
#define HID 4096
#define NE 8
#define MAXMB 72

#define WAITV(n) asm volatile("s_waitcnt vmcnt(" #n ")" ::: "memory")

__device__ __forceinline__ void wgbar() {
  asm volatile("" ::: "memory");
  __builtin_amdgcn_s_barrier();
  asm volatile("" ::: "memory");
}

__device__ __forceinline__ u16 f2bf(float f) {
  unsigned u = __float_as_uint(f);
  u += 0x7fffu + ((u >> 16) & 1u);   // round-to-nearest-even
  return (u16)(u >> 16);
}

__device__ __forceinline__ void gload16(const u16* g, u16* l) {
  __builtin_amdgcn_global_load_lds(
      (const __attribute__((address_space(1))) unsigned int*)g,
      (__attribute__((address_space(3))) unsigned int*)l, 16, 0, 0);
}

__global__ void init_kernel(int* counts) {
  if (threadIdx.x < NE) counts[threadIdx.x] = 0;
}

// gate + x->bf16 conversion fused (gate already reads every x element)
__global__ __launch_bounds__(256) void gate_kernel(
    const float* __restrict__ x, const float* __restrict__ gw,
    const float* __restrict__ gb, int* __restrict__ counts,
    int* __restrict__ tlist, int* __restrict__ eid, int* __restrict__ pos,
    float* __restrict__ wgt, u16* __restrict__ xb) {
  int t = blockIdx.x * 4 + (threadIdx.x >> 6);
  int lane = threadIdx.x & 63;
  float acc[NE];
  #pragma unroll
  for (int e = 0; e < NE; ++e) acc[e] = 0.f;
  const float* xr = x + (size_t)t * DIM;
  u16* xbr = xb + (size_t)t * DIM;
  for (int d = lane; d < DIM; d += 64) {
    float xv = xr[d];
    xbr[d] = f2bf(xv);
    const float* g = gw + d * NE;
    #pragma unroll
    for (int e = 0; e < NE; ++e) acc[e] += xv * g[e];
  }
  #pragma unroll
  for (int off = 32; off > 0; off >>= 1) {
    #pragma unroll
    for (int e = 0; e < NE; ++e) acc[e] += __shfl_down(acc[e], off);
  }
  if (lane == 0) {
    #pragma unroll
    for (int e = 0; e < NE; ++e) acc[e] += gb[e];
    int i0 = 0; float v0 = acc[0];
    #pragma unroll
    for (int e = 1; e < NE; ++e) if (acc[e] > v0) { v0 = acc[e]; i0 = e; }
    int i1 = -1; float v1 = -1e30f;
    #pragma unroll
    for (int e = 0; e < NE; ++e) if (e != i0 && acc[e] > v1) { v1 = acc[e]; i1 = e; }
    float z = expf(v1 - v0);            // v0 >= v1
    float s0 = 1.f / (1.f + z);
    float s1 = z / (1.f + z);
    int p0 = atomicAdd(&counts[i0], 1);
    tlist[i0 * N_TOK + p0] = t * 2 + 0;
    eid[2 * t] = i0; pos[2 * t] = p0; wgt[2 * t] = s0;
    int p1 = atomicAdd(&counts[i1], 1);
    tlist[i1 * N_TOK + p1] = t * 2 + 1;
    eid[2 * t + 1] = i1; pos[2 * t + 1] = p1; wgt[2 * t + 1] = s1;
  }
}

// Builds dense m-block schedule: experts padded to 128-row slot regions.
__global__ void scan_kernel(const int* __restrict__ counts, int* __restrict__ offs,
                            int* __restrict__ poffs, int* __restrict__ nmb,
                            int* __restrict__ mb2e, int* __restrict__ mb2m0) {
  if (threadIdx.x == 0) {
    int s = 0, p = 0, mb = 0;
    for (int e = 0; e < NE; ++e) {
      offs[e] = s; poffs[e] = p;
      int nb = (counts[e] + 127) >> 7;
      for (int i = 0; i < nb; ++i) { mb2e[mb] = e; mb2m0[mb] = i * 128; ++mb; }
      s += counts[e]; p += nb * 128;
    }
    offs[NE] = s; poffs[NE] = p;
    nmb[0] = mb;
    for (int i = mb; i < MAXMB; ++i) { mb2e[i] = 0; mb2m0[i] = 0; }
  }
}

// Both weight transposes in one launch. bid<8192: w1[e][D][H]->w1t[e][H][D];
// else w2[e][H][D]->w2t[e][D][H]. 1024 64x64 tiles per expert either way.
__global__ __launch_bounds__(256) void transpose_all_kernel(
    const float* __restrict__ w1, const float* __restrict__ w2,
    u16* __restrict__ w1t, u16* __restrict__ w2t) {
  __shared__ u16 tile[64][65];
  int bid = blockIdx.x;
  const float* in; u16* out; int R, C, csh, rem;
  if (bid < 8192) { in = w1; out = w1t; R = DIM; C = HID; csh = 6; rem = bid; }
  else           { in = w2; out = w2t; R = HID; C = DIM; csh = 4; rem = bid - 8192; }
  int e = rem >> 10;
  int r2 = rem & 1023;
  int rt = r2 >> csh;
  int ct = r2 & ((1 << csh) - 1);
  int r0 = rt * 64, c0 = ct * 64;
  int tid = threadIdx.x;
  int rr = tid >> 4;          // 0..15
  int cc = (tid & 15) * 4;    // 0..60
  const float* src = in + (size_t)e * R * C + (size_t)r0 * C + c0;
  #pragma unroll
  for (int rd = 0; rd < 4; ++rd) {
    int r = rd * 16 + rr;
    float4 v = *(const float4*)&src[(size_t)r * C + cc];
    tile[r][cc + 0] = f2bf(v.x);
    tile[r][cc + 1] = f2bf(v.y);
    tile[r][cc + 2] = f2bf(v.z);
    tile[r][cc + 3] = f2bf(v.w);
  }
  __syncthreads();
  u16* dst = out + (size_t)e * R * C + (size_t)c0 * R + r0;
  #pragma unroll
  for (int rd = 0; rd < 4; ++rd) {
    int oc = rd * 16 + rr;    // output row (= input col)
    u16x4 o;
    o[0] = tile[cc + 0][oc];
    o[1] = tile[cc + 1][oc];
    o[2] = tile[cc + 2][oc];
    o[3] = tile[cc + 3][oc];
    *(u16x4*)&dst[(size_t)oc * R + cc] = o;
  }
}

// GEMM1: h[pslot, H] = relu(x[token, D] * w1t[e]^T + b1[e]) -> bf16
// 128x128, BK=64, 2-stage, counted vmcnt (T3+T4), R7 conflict-free 8-slot XOR,
// T1 chunked XCD swizzle (2304 = 8 x 288, mb-major flatten).
__global__ __launch_bounds__(256) void gemm1_kernel(
    const u16* __restrict__ xb, const u16* __restrict__ w1t,
    const float* __restrict__ b1, const int* __restrict__ counts,
    const int* __restrict__ poffs, const int* __restrict__ nmb,
    const int* __restrict__ mb2e, const int* __restrict__ mb2m0,
    const int* __restrict__ tlist, u16* __restrict__ hbuf) {
  int bid = blockIdx.x;
  int swz = (bid & 7) * 288 + (bid >> 3);
  int mb = swz >> 5;
  if (mb >= nmb[0]) return;
  int n0 = (swz & 31) << 7;
  int e = mb2e[mb];
  int m0 = mb2m0[mb];
  int ne = counts[e];
  int tid = threadIdx.x;

  __shared__ u16 lds[32768];   // 2 stages x (A 8192 | B 8192) u16 = 64KB

  int rsub = tid >> 3;                          // 0..31 row sub-index
  int kch  = ((tid & 7) ^ (rsub & 7)) * 8;      // pre-swizzled source chunk
  const u16* aSrc[4];
  const u16* bSrc[4];
  #pragma unroll
  for (int j = 0; j < 4; ++j) {
    int r = m0 + j * 32 + rsub;
    int idx = r < ne ? r : ne - 1;
    aSrc[j] = xb + (size_t)(tlist[e * N_TOK + idx] >> 1) * DIM + kch;
    bSrc[j] = w1t + ((size_t)e * HID + n0 + j * 32 + rsub) * DIM + kch;
  }

#define STG(kk, s) do { \
    gload16(aSrc[0] + (kk), &lds[(s) * 16384 + 0 * 2048 + tid * 8]); \
    gload16(aSrc[1] + (kk), &lds[(s) * 16384 + 1 * 2048 + tid * 8]); \
    gload16(aSrc[2] + (kk), &lds[(s) * 16384 + 2 * 2048 + tid * 8]); \
    gload16(aSrc[3] + (kk), &lds[(s) * 16384 + 3 * 2048 + tid * 8]); \
    gload16(bSrc[0] + (kk), &lds[(s) * 16384 + 8192 + 0 * 2048 + tid * 8]); \
    gload16(bSrc[1] + (kk), &lds[(s) * 16384 + 8192 + 1 * 2048 + tid * 8]); \
    gload16(bSrc[2] + (kk), &lds[(s) * 16384 + 8192 + 2 * 2048 + tid * 8]); \
    gload16(bSrc[3] + (kk), &lds[(s) * 16384 + 8192 + 3 * 2048 + tid * 8]); } while (0)

  int lane = tid & 63;
  int wv = tid >> 6;
  int wr = (wv >> 1) * 64, wc = (wv & 1) * 64;
  int fr = lane & 15, fq = lane >> 4;

  f32x4 acc[4][4];
  #pragma unroll
  for (int m = 0; m < 4; ++m)
    #pragma unroll
    for (int n = 0; n < 4; ++n) { f32x4 z = {0.f, 0.f, 0.f, 0.f}; acc[m][n] = z; }

  STG(0, 0);
  for (int t = 0; t < 16; ++t) {
    int cs = t & 1;
    if (t < 15) { STG((t + 1) * 64, cs ^ 1); WAITV(8); }
    else        { WAITV(0); }
    wgbar();
    {
      const u16* Ab = &lds[cs * 16384];
      const u16* Bb = &lds[cs * 16384 + 8192];
      __builtin_amdgcn_s_setprio(1);
      #pragma unroll
      for (int th = 0; th < 2; ++th) {
        s16x8 af[4], bf_[4];
        #pragma unroll
        for (int m = 0; m < 4; ++m) {
          int row = wr + m * 16 + fr;
          af[m] = *(const s16x8*)&Ab[row * 64 + (((th * 4 + fq) ^ (row & 7)) * 8)];
        }
        #pragma unroll
        for (int n = 0; n < 4; ++n) {
          int row = wc + n * 16 + fr;
          bf_[n] = *(const s16x8*)&Bb[row * 64 + (((th * 4 + fq) ^ (row & 7)) * 8)];
        }
        #pragma unroll
        for (int m = 0; m < 4; ++m)
          #pragma unroll
          for (int n = 0; n < 4; ++n)
            acc[m][n] = __builtin_amdgcn_mfma_f32_16x16x32_bf16(af[m], bf_[n], acc[m][n], 0, 0, 0);
      }
      __builtin_amdgcn_s_setprio(0);
    }
    wgbar();
  }
#undef STG

  int pbase = poffs[e] + m0;
  float bias[4];
  #pragma unroll
  for (int n = 0; n < 4; ++n) bias[n] = b1[e * HID + n0 + wc + n * 16 + fr];
  #pragma unroll
  for (int m = 0; m < 4; ++m) {
    #pragma unroll
    for (int j = 0; j < 4; ++j) {
      int row = wr + m * 16 + fq * 4 + j;
      if (m0 + row < ne) {
        u16* hr = hbuf + (size_t)(pbase + row) * HID + n0;
        #pragma unroll
        for (int n = 0; n < 4; ++n) {
          int col = wc + n * 16 + fr;
          float v = acc[m][n][j] + bias[n];
          hr[col] = f2bf(fmaxf(v, 0.f));
        }
      }
    }
  }
}

// GEMM2: y[pslot, D] = h[pslot, H] * w2t[e]^T + b2[e] -> fp32
// same pipeline; split-K x2; T1 chunked swizzle (1152 = 8 x 144).
__global__ __launch_bounds__(256) void gemm2_kernel(
    const u16* __restrict__ hbuf, const u16* __restrict__ w2t,
    const float* __restrict__ b2, const int* __restrict__ counts,
    const int* __restrict__ poffs, const int* __restrict__ nmb,
    const int* __restrict__ mb2e, const int* __restrict__ mb2m0,
    float* __restrict__ yb0, float* __restrict__ yb1) {
  int bid = blockIdx.x;
  int swz = (bid & 7) * 144 + (bid >> 3);
  int mb = swz >> 4;
  if (mb >= nmb[0]) return;
  int rest = swz & 15;
  int z = rest >> 3;
  int n0 = (rest & 7) << 7;
  int e = mb2e[mb];
  int m0 = mb2m0[mb];
  int ne = counts[e];
  int kz = z * (HID / 2);
  int tid = threadIdx.x;
  int pbase = poffs[e] + m0;

  __shared__ u16 lds[32768];

  int rsub = tid >> 3;
  int kch  = ((tid & 7) ^ (rsub & 7)) * 8;
  const u16* aSrc[4];
  const u16* bSrc[4];
  #pragma unroll
  for (int j = 0; j < 4; ++j) {
    int r = m0 + j * 32 + rsub;
    int idx = r < ne ? r : ne - 1;
    aSrc[j] = hbuf + (size_t)(poffs[e] + idx) * HID + kz + kch;
    bSrc[j] = w2t + ((size_t)e * DIM + n0 + j * 32 + rsub) * HID + kz + kch;
  }

#define STG(kk, s) do { \
    gload16(aSrc[0] + (kk), &lds[(s) * 16384 + 0 * 2048 + tid * 8]); \
    gload16(aSrc[1] + (kk), &lds[(s) * 16384 + 1 * 2048 + tid * 8]); \
    gload16(aSrc[2] + (kk), &lds[(s) * 16384 + 2 * 2048 + tid * 8]); \
    gload16(aSrc[3] + (kk), &lds[(s) * 16384 + 3 * 2048 + tid * 8]); \
    gload16(bSrc[0] + (kk), &lds[(s) * 16384 + 8192 + 0 * 2048 + tid * 8]); \
    gload16(bSrc[1] + (kk), &lds[(s) * 16384 + 8192 + 1 * 2048 + tid * 8]); \
    gload16(bSrc[2] + (kk), &lds[(s) * 16384 + 8192 + 2 * 2048 + tid * 8]); \
    gload16(bSrc[3] + (kk), &lds[(s) * 16384 + 8192 + 3 * 2048 + tid * 8]); } while (0)

  int lane = tid & 63;
  int wv = tid >> 6;
  int wr = (wv >> 1) * 64, wc = (wv & 1) * 64;
  int fr = lane & 15, fq = lane >> 4;

  f32x4 acc[4][4];
  #pragma unroll
  for (int m = 0; m < 4; ++m)
    #pragma unroll
    for (int n = 0; n < 4; ++n) { f32x4 z2 = {0.f, 0.f, 0.f, 0.f}; acc[m][n] = z2; }

  STG(0, 0);
  for (int t = 0; t < 32; ++t) {
    int cs = t & 1;
    if (t < 31) { STG((t + 1) * 64, cs ^ 1); WAITV(8); }
    else        { WAITV(0); }
    wgbar();
    {
      const u16* Ab = &lds[cs * 16384];
      const u16* Bb = &lds[cs * 16384 + 8192];
      __builtin_amdgcn_s_setprio(1);
      #pragma unroll
      for (int th = 0; th < 2; ++th) {
        s16x8 af[4], bf_[4];
        #pragma unroll
        for (int m = 0; m < 4; ++m) {
          int row = wr + m * 16 + fr;
          af[m] = *(const s16x8*)&Ab[row * 64 + (((th * 4 + fq) ^ (row & 7)) * 8)];
        }
        #pragma unroll
        for (int n = 0; n < 4; ++n) {
          int row = wc + n * 16 + fr;
          bf_[n] = *(const s16x8*)&Bb[row * 64 + (((th * 4 + fq) ^ (row & 7)) * 8)];
        }
        #pragma unroll
        for (int m = 0; m < 4; ++m)
          #pragma unroll
          for (int n = 0; n < 4; ++n)
            acc[m][n] = __builtin_amdgcn_mfma_f32_16x16x32_bf16(af[m], bf_[n], acc[m][n], 0, 0, 0);
      }
      __builtin_amdgcn_s_setprio(0);
    }
    wgbar();
  }
#undef STG

  float* yb = z ? yb1 : yb0;
  float bias[4];
  #pragma unroll
  for (int n = 0; n < 4; ++n)
    bias[n] = (z == 0) ? b2[e * DIM + n0 + wc + n * 16 + fr] : 0.f;
  #pragma unroll
  for (int m = 0; m < 4; ++m) {
    #pragma unroll
    for (int j = 0; j < 4; ++j) {
      int row = wr + m * 16 + fq * 4 + j;
      if (m0 + row < ne) {
        float* yr = yb + (size_t)(pbase + row) * DIM + n0;
        #pragma unroll
        for (int n = 0; n < 4; ++n) {
          int col = wc + n * 16 + fr;
          yr[col] = acc[m][n][j] + bias[n];
        }
      }
    }
  }
}

__global__ __launch_bounds__(256) void combine_kernel(
    const int* __restrict__ eid, const int* __restrict__ pos,
    const float* __restrict__ wgt, const int* __restrict__ poffs,
    const float* __restrict__ yb0, const float* __restrict__ yb1,
    float* __restrict__ out) {
  int t = blockIdx.x;
  int e0 = eid[2 * t], e1 = eid[2 * t + 1];
  float w0 = wgt[2 * t], w1v = wgt[2 * t + 1];
  size_t g0 = (size_t)(poffs[e0] + pos[2 * t]) * DIM;
  size_t g1 = (size_t)(poffs[e1] + pos[2 * t + 1]) * DIM;
  int d = threadIdx.x * 4;
  float4 a0 = *(const float4*)&yb0[g0 + d];
  float4 a1 = *(const float4*)&yb1[g0 + d];
  float4 b0 = *(const float4*)&yb0[g1 + d];
  float4 b1v = *(const float4*)&yb1[g1 + d];
  float4 o;
  o.x = w0 * (a0.x + a1.x) + w1v * (b0.x + b1v.x);
  o.y = w0 * (a0.y + a1.y) + w1v * (b0.y + b1v.y);
  o.z = w0 * (a0.z + a1.z) + w1v * (b0.z + b1v.z);
  o.w = w0 * (a0.w + a1.w) + w1v * (b0.w + b1v.w);
  *(float4*)&out[(size_t)t * DIM + d] = o;
}

extern "C" void kernel_launch(void* const* d_in, const int* in_sizes, int n_in,
                              void* d_out, int out_size, void* d_ws, size_t ws_size,
                              hipStream_t stream) {
  const float* x  = (const float*)d_in[0];
  const float* gw = (const float*)d_in[1];
  const float* gb = (const float*)d_in[2];
  const float* w1 = (const float*)d_in[3];
  const float* b1 = (const float*)d_in[4];
  const float* w2 = (const float*)d_in[5];
  const float* b2 = (const float*)d_in[6];
  float* out = (float*)d_out;

  char* ws = (char*)d_ws;
  const size_t MB = 1ull << 20;
  // layout: [0,64)   w1t   (dead after gemm1; yb0 36MB aliases here)
  //         [64,128) w2t
  //         [128,136) xb
  //         [136,208) hbuf (9216*4096*2B = 72MB)
  //         [208,244) yb1 (9216*1024*4B = 36MB)
  //         [244,...) meta
  u16*   w1t    = (u16*)(ws);
  float* yb0    = (float*)(ws);              // aliases w1t (dead before gemm2)
  u16*   w2t    = (u16*)(ws + 64 * MB);
  u16*   xb     = (u16*)(ws + 128 * MB);
  u16*   hbuf   = (u16*)(ws + 136 * MB);
  float* yb1    = (float*)(ws + 208 * MB);
  char*  meta   = ws + 244 * MB;
  int*   eid    = (int*)(meta);
  int*   pos    = (int*)(meta + 32 * 1024);
  float* wgt    = (float*)(meta + 64 * 1024);
  int*   counts = (int*)(meta + 96 * 1024);
  int*   offs   = (int*)(meta + 96 * 1024 + 256);
  int*   poffs  = (int*)(meta + 96 * 1024 + 512);
  int*   nmb    = (int*)(meta + 96 * 1024 + 768);
  int*   mb2e   = (int*)(meta + 96 * 1024 + 1024);
  int*   mb2m0  = (int*)(meta + 96 * 1024 + 2048);
  int*   tlist  = (int*)(meta + 128 * 1024);

  init_kernel<<<1, 64, 0, stream>>>(counts);
  gate_kernel<<<N_TOK / 4, 256, 0, stream>>>(x, gw, gb, counts, tlist, eid, pos, wgt, xb);
  scan_kernel<<<1, 64, 0, stream>>>(counts, offs, poffs, nmb, mb2e, mb2m0);
  transpose_all_kernel<<<16384, 256, 0, stream>>>(w1, w2, w1t, w2t);
  gemm1_kernel<<<2304, 256, 0, stream>>>(xb, w1t, b1, counts, poffs, nmb, mb2e, mb2m0, tlist, hbuf);
  gemm2_kernel<<<1152, 256, 0, stream>>>(hbuf, w2t, b2, counts, poffs, nmb, mb2e, mb2m0, yb0, yb1);
  combine_kernel<<<N_TOK, 256, 0, stream>>>(eid, pos, wgt, poffs, yb0, yb1, out);
}